// Round 6
// baseline (149.390 us; speedup 1.0000x reference)
//
#include <hip/hip_runtime.h>
#include <math.h>

#define NN 50000
#define NE 800000
#define NH 4
#define HD 32
#define FD 128   // NH*HD == IN_DIM
#define NTILE 3125  // 50000 / 16 exactly

typedef __attribute__((ext_vector_type(8))) short short8;
typedef __attribute__((ext_vector_type(4))) float floatx4;

__device__ __forceinline__ unsigned short f2bf(float f) {
    union { float f; unsigned u; } v; v.f = f;
    unsigned u = v.u;
    return (unsigned short)((u + 0x7FFFu + ((u >> 16) & 1u)) >> 16);
}
__device__ __forceinline__ float bf_lo(unsigned u) {
    union { unsigned u; float f; } v; v.u = u << 16; return v.f;
}
__device__ __forceinline__ float bf_hi(unsigned u) {
    union { unsigned u; float f; } v; v.u = u & 0xFFFF0000u; return v.f;
}

// ---------------------------------------------------------------------------
// Kernel 0: G[j][k] (16x128 bf16): attn-folded weight rows for fused el/er.
// G[j] = sum_d a[h,d] W[32h+d,:]  (j<4: al head j; j in 4..7: er head j-4).
// Coalesced: threads k=0..127 read consecutive W elements per d.
// ---------------------------------------------------------------------------
__global__ void k_prep(const float* __restrict__ W,
                       const float* __restrict__ al,
                       const float* __restrict__ ar,
                       unsigned short* __restrict__ Gbf) {
    int p = blockIdx.x * blockDim.x + threadIdx.x;
    if (p >= 16 * 128) return;
    int j = p >> 7, k = p & 127;
    float g = 0.f;
    if (j < 8) {
        int hh = j & 3;
        const float* av = (j < 4) ? al : ar;
        #pragma unroll
        for (int d = 0; d < 32; ++d)
            g += av[hh * 32 + d] * W[(size_t)(hh * 32 + d) * FD + k];
    }
    Gbf[p] = f2bf(g);
}

// ---------------------------------------------------------------------------
// Kernel 1: projection via bf16 MFMA + fused el/er (extra MFMA with G tile).
// ---------------------------------------------------------------------------
__global__ __launch_bounds__(512) void k_gemm(const float* __restrict__ x,
                                              const float* __restrict__ W,
                                              const unsigned short* __restrict__ Gbf,
                                              unsigned short* __restrict__ feat_bf,
                                              float* __restrict__ el,
                                              float* __restrict__ er) {
    __shared__ unsigned short Wl[FD * 136];   // Wl[c][k], row stride 136
    __shared__ unsigned short ABl[16 * 136];
    const int tid = threadIdx.x;

    for (int p = tid; p < FD * 64; p += 512) {
        int c = p >> 6, k2 = (p & 63) * 2;
        float2 wv = *(const float2*)&W[c * FD + k2];
        *(unsigned*)&Wl[c * 136 + k2] =
            (unsigned)f2bf(wv.x) | ((unsigned)f2bf(wv.y) << 16);
    }
    for (int p = tid; p < 16 * 128; p += 512) {
        int j = p >> 7, k = p & 127;
        ABl[j * 136 + k] = Gbf[p];
    }
    __syncthreads();

    const int wv_id = tid >> 6, lane = tid & 63;
    const int col = lane & 15, quad = lane >> 4;

    for (int tile = blockIdx.x * 8 + wv_id; tile < NTILE; tile += gridDim.x * 8) {
        const int n0 = tile * 16;

        short8 afrag[4];
        const float* xrow = x + (size_t)(n0 + col) * FD;
        #pragma unroll
        for (int s = 0; s < 4; ++s) {
            float4 u0 = *(const float4*)&xrow[s * 32 + quad * 8];
            float4 u1 = *(const float4*)&xrow[s * 32 + quad * 8 + 4];
            short8 a;
            a[0] = (short)f2bf(u0.x); a[1] = (short)f2bf(u0.y);
            a[2] = (short)f2bf(u0.z); a[3] = (short)f2bf(u0.w);
            a[4] = (short)f2bf(u1.x); a[5] = (short)f2bf(u1.y);
            a[6] = (short)f2bf(u1.z); a[7] = (short)f2bf(u1.w);
            afrag[s] = a;
        }

        floatx4 acc[8];
        floatx4 accE = (floatx4){0.f, 0.f, 0.f, 0.f};
        #pragma unroll
        for (int ct = 0; ct < 8; ++ct) acc[ct] = (floatx4){0.f, 0.f, 0.f, 0.f};

        #pragma unroll
        for (int ct = 0; ct < 8; ++ct) {
            #pragma unroll
            for (int s = 0; s < 4; ++s) {
                short8 b = *(const short8*)&Wl[(ct * 16 + col) * 136 + s * 32 + quad * 8];
                acc[ct] = __builtin_amdgcn_mfma_f32_16x16x32_bf16(afrag[s], b, acc[ct], 0, 0, 0);
            }
        }
        #pragma unroll
        for (int s = 0; s < 4; ++s) {
            short8 b = *(const short8*)&ABl[col * 136 + s * 32 + quad * 8];
            accE = __builtin_amdgcn_mfma_f32_16x16x32_bf16(afrag[s], b, accE, 0, 0, 0);
        }

        #pragma unroll
        for (int ct = 0; ct < 8; ++ct) {
            #pragma unroll
            for (int r = 0; r < 4; ++r) {
                feat_bf[(size_t)(n0 + quad * 4 + r) * FD + ct * 16 + col] = f2bf(acc[ct][r]);
            }
        }
        if (col < 8) {
            float* base = (col < 4) ? el : er;
            int hh = col & 3;
            #pragma unroll
            for (int r = 0; r < 4; ++r)
                base[(n0 + quad * 4 + r) * NH + hh] = accE[r];
        }
    }
}

// ---------------------------------------------------------------------------
// Kernel 2: per-edge weights wP[e][h] (float4/edge, coalesced for aggregate)
// + fused CSR row offsets. Unshifted exp is exact-safe (logits sigma ~0.23).
// ---------------------------------------------------------------------------
__global__ void k_edgew(const float* __restrict__ el,
                        const float* __restrict__ er,
                        const int* __restrict__ src,
                        const int* __restrict__ dst,
                        float* __restrict__ wP,
                        int* __restrict__ rows) {
    int e = blockIdx.x * blockDim.x + threadIdx.x;
    if (e >= NE) return;
    int sj = src[e], dj = dst[e];

    if (e == 0) {
        for (int n = 0; n <= dj; ++n) rows[n] = 0;
    } else {
        int prev = dst[e - 1];
        for (int n = prev + 1; n <= dj; ++n) rows[n] = e;
    }
    if (e == NE - 1) {
        for (int n = dj + 1; n <= NN; ++n) rows[n] = NE;
    }

    float4 el4 = *(const float4*)&el[sj * NH];
    float4 er4 = *(const float4*)&er[dj * NH];
    float4 w;
    float lg, z;
    lg = el4.x + er4.x; z = fmaxf(lg, 0.2f * lg); w.x = __expf(z);
    lg = el4.y + er4.y; z = fmaxf(lg, 0.2f * lg); w.y = __expf(z);
    lg = el4.z + er4.z; z = fmaxf(lg, 0.2f * lg); w.z = __expf(z);
    lg = el4.w + er4.w; z = fmaxf(lg, 0.2f * lg); w.w = __expf(z);
    *(float4*)&wP[e * NH] = w;
}

// ---------------------------------------------------------------------------
// Kernel 3: aggregation. TWO independent nodes per wave (doubled MLP: up to
// 8 uint4 gathers in flight). Per node: 4 edge slots x 16 dim lanes.
// All loop conditions are wave-uniform (cheap s_cbranch, no divergence).
// ---------------------------------------------------------------------------
__global__ __launch_bounds__(256) void k_aggregate(const unsigned short* __restrict__ feat_bf,
                                                   const float* __restrict__ wP,
                                                   const int* __restrict__ src,
                                                   const int* __restrict__ rows,
                                                   float* __restrict__ out) {
    const int wave = threadIdx.x >> 6;
    const int lane = threadIdx.x & 63;
    const int pair = blockIdx.x * 4 + wave;
    const int n0 = pair * 2;
    if (n0 >= NN) return;
    const int n1 = n0 + 1;   // NN even -> always valid

    const int q  = lane >> 4;
    const int lp = lane & 15;
    const int h  = lp >> 2;
    const int dimoff = 8 * lp;

    const int s0 = rows[n0], t0 = rows[n0 + 1];
    const int s1 = rows[n1], t1 = rows[n1 + 1];

    float acc0[8] = {0.f,0.f,0.f,0.f,0.f,0.f,0.f,0.f};
    float acc1[8] = {0.f,0.f,0.f,0.f,0.f,0.f,0.f,0.f};
    float den0 = 0.f, den1 = 0.f;

    int e0 = s0, e1 = s1;
    while ((e0 < t0) || (e1 < t1)) {
        const bool a0 = e0 < t0, a1 = e1 < t1;   // wave-uniform
        int   sj0[4], sj1[4];
        float w0[4],  w1[4];
        if (a0) {
            #pragma unroll
            for (int u = 0; u < 4; ++u) {
                int ei = e0 + 4 * u + q;
                int ec = (ei < t0) ? ei : (t0 - 1);
                sj0[u] = src[ec];
                w0[u]  = (ei < t0) ? wP[ec * NH + h] : 0.f;
            }
        }
        if (a1) {
            #pragma unroll
            for (int u = 0; u < 4; ++u) {
                int ei = e1 + 4 * u + q;
                int ec = (ei < t1) ? ei : (t1 - 1);
                sj1[u] = src[ec];
                w1[u]  = (ei < t1) ? wP[ec * NH + h] : 0.f;
            }
        }
        uint4 f0[4], f1[4];
        if (a0) {
            #pragma unroll
            for (int u = 0; u < 4; ++u)
                f0[u] = *(const uint4*)&feat_bf[(size_t)sj0[u] * FD + dimoff];
        }
        if (a1) {
            #pragma unroll
            for (int u = 0; u < 4; ++u)
                f1[u] = *(const uint4*)&feat_bf[(size_t)sj1[u] * FD + dimoff];
        }
        if (a0) {
            #pragma unroll
            for (int u = 0; u < 4; ++u) {
                float w = w0[u]; uint4 uv = f0[u];
                acc0[0] += w * bf_lo(uv.x); acc0[1] += w * bf_hi(uv.x);
                acc0[2] += w * bf_lo(uv.y); acc0[3] += w * bf_hi(uv.y);
                acc0[4] += w * bf_lo(uv.z); acc0[5] += w * bf_hi(uv.z);
                acc0[6] += w * bf_lo(uv.w); acc0[7] += w * bf_hi(uv.w);
                den0 += w;
            }
            e0 += 16;
        }
        if (a1) {
            #pragma unroll
            for (int u = 0; u < 4; ++u) {
                float w = w1[u]; uint4 uv = f1[u];
                acc1[0] += w * bf_lo(uv.x); acc1[1] += w * bf_hi(uv.x);
                acc1[2] += w * bf_lo(uv.y); acc1[3] += w * bf_hi(uv.y);
                acc1[4] += w * bf_lo(uv.z); acc1[5] += w * bf_hi(uv.z);
                acc1[6] += w * bf_lo(uv.w); acc1[7] += w * bf_hi(uv.w);
                den1 += w;
            }
            e1 += 16;
        }
    }

    // combine the 4 edge-slot groups (lanes differing in bits 4,5)
    #pragma unroll
    for (int m = 16; m < 64; m <<= 1) {
        #pragma unroll
        for (int j = 0; j < 8; ++j) {
            acc0[j] += __shfl_xor(acc0[j], m);
            acc1[j] += __shfl_xor(acc1[j], m);
        }
        den0 += __shfl_xor(den0, m);
        den1 += __shfl_xor(den1, m);
    }

    if (q == 0) {
        const float rd = (den0 > 0.f) ? 1.f / den0 : 0.f;
        float* op = out + (size_t)n0 * FD + dimoff;
        *(float4*)op       = make_float4(acc0[0] * rd, acc0[1] * rd, acc0[2] * rd, acc0[3] * rd);
        *(float4*)(op + 4) = make_float4(acc0[4] * rd, acc0[5] * rd, acc0[6] * rd, acc0[7] * rd);
    } else if (q == 1) {
        const float rd = (den1 > 0.f) ? 1.f / den1 : 0.f;
        float* op = out + (size_t)n1 * FD + dimoff;
        *(float4*)op       = make_float4(acc1[0] * rd, acc1[1] * rd, acc1[2] * rd, acc1[3] * rd);
        *(float4*)(op + 4) = make_float4(acc1[4] * rd, acc1[5] * rd, acc1[6] * rd, acc1[7] * rd);
    }
}

// ---------------------------------------------------------------------------
extern "C" void kernel_launch(void* const* d_in, const int* in_sizes, int n_in,
                              void* d_out, int out_size, void* d_ws, size_t ws_size,
                              hipStream_t stream) {
    const float* x  = (const float*)d_in[0];
    const float* W  = (const float*)d_in[1];
    const float* al = (const float*)d_in[2];
    const float* ar = (const float*)d_in[3];
    const int* src  = (const int*)d_in[4];
    const int* dst  = (const int*)d_in[5];
    float* out = (float*)d_out;

    // ws: feat_bf[NN*FD] ushort | el[NN*NH] | er[NN*NH] | rows[NN+1] | wP[NE*NH] | Gbf[16*128]
    unsigned short* feat_bf = (unsigned short*)d_ws;
    float* el = (float*)(feat_bf + (size_t)NN * FD);
    float* er = el + (size_t)NN * NH;
    int*   rows = (int*)(er + (size_t)NN * NH);
    float* wP = (float*)(((uintptr_t)(rows + NN + 1) + 15) & ~(uintptr_t)15);
    unsigned short* Gbf = (unsigned short*)(wP + (size_t)NE * NH);

    k_prep<<<8, 256, 0, stream>>>(W, al, ar, Gbf);
    k_gemm<<<512, 512, 0, stream>>>(x, W, Gbf, feat_bf, el, er);
    k_edgew<<<(NE + 255) / 256, 256, 0, stream>>>(el, er, src, dst, wP, rows);
    k_aggregate<<<(NN / 2 + 3) / 4, 256, 0, stream>>>(feat_bf, wP, src, rows, out);
}

// Round 7
// 139.007 us; speedup vs baseline: 1.0747x; 1.0747x over previous
//
#include <hip/hip_runtime.h>
#include <math.h>

#define NN 50000
#define NE 800000
#define NH 4
#define HD 32
#define FD 128   // NH*HD == IN_DIM
#define NTILE 3125  // 50000 / 16 exactly

typedef __attribute__((ext_vector_type(8))) short short8;
typedef __attribute__((ext_vector_type(4))) float floatx4;

__device__ __forceinline__ unsigned short f2bf(float f) {
    union { float f; unsigned u; } v; v.f = f;
    unsigned u = v.u;
    return (unsigned short)((u + 0x7FFFu + ((u >> 16) & 1u)) >> 16);
}
__device__ __forceinline__ float bf_lo(unsigned u) {
    union { unsigned u; float f; } v; v.u = u << 16; return v.f;
}
__device__ __forceinline__ float bf_hi(unsigned u) {
    union { unsigned u; float f; } v; v.u = u & 0xFFFF0000u; return v.f;
}

// ---------------------------------------------------------------------------
// Kernel 0: G[j][k] (16x128 bf16): attn-folded weight rows for fused el/er.
// G[j] = sum_d a[h,d] W[32h+d,:]  (j<4: al head j; j 4..7: ar head j-4).
// ---------------------------------------------------------------------------
__global__ void k_prep(const float* __restrict__ W,
                       const float* __restrict__ al,
                       const float* __restrict__ ar,
                       unsigned short* __restrict__ Gbf) {
    int p = blockIdx.x * blockDim.x + threadIdx.x;
    if (p >= 16 * 128) return;
    int j = p >> 7, k = p & 127;
    float g = 0.f;
    if (j < 8) {
        int hh = j & 3;
        const float* av = (j < 4) ? al : ar;
        #pragma unroll
        for (int d = 0; d < 32; ++d)
            g += av[hh * 32 + d] * W[(size_t)(hh * 32 + d) * FD + k];
    }
    Gbf[p] = f2bf(g);
}

// ---------------------------------------------------------------------------
// Kernel 1: projection via bf16 MFMA + fused el/er (extra MFMA with G tile).
// ---------------------------------------------------------------------------
__global__ __launch_bounds__(512) void k_gemm(const float* __restrict__ x,
                                              const float* __restrict__ W,
                                              const unsigned short* __restrict__ Gbf,
                                              unsigned short* __restrict__ feat_bf,
                                              float* __restrict__ el,
                                              float* __restrict__ er) {
    __shared__ unsigned short Wl[FD * 136];   // Wl[c][k], row stride 136
    __shared__ unsigned short ABl[16 * 136];
    const int tid = threadIdx.x;

    for (int p = tid; p < FD * 64; p += 512) {
        int c = p >> 6, k2 = (p & 63) * 2;
        float2 wv = *(const float2*)&W[c * FD + k2];
        *(unsigned*)&Wl[c * 136 + k2] =
            (unsigned)f2bf(wv.x) | ((unsigned)f2bf(wv.y) << 16);
    }
    for (int p = tid; p < 16 * 128; p += 512) {
        int j = p >> 7, k = p & 127;
        ABl[j * 136 + k] = Gbf[p];
    }
    __syncthreads();

    const int wv_id = tid >> 6, lane = tid & 63;
    const int col = lane & 15, quad = lane >> 4;

    for (int tile = blockIdx.x * 8 + wv_id; tile < NTILE; tile += gridDim.x * 8) {
        const int n0 = tile * 16;

        short8 afrag[4];
        const float* xrow = x + (size_t)(n0 + col) * FD;
        #pragma unroll
        for (int s = 0; s < 4; ++s) {
            float4 u0 = *(const float4*)&xrow[s * 32 + quad * 8];
            float4 u1 = *(const float4*)&xrow[s * 32 + quad * 8 + 4];
            short8 a;
            a[0] = (short)f2bf(u0.x); a[1] = (short)f2bf(u0.y);
            a[2] = (short)f2bf(u0.z); a[3] = (short)f2bf(u0.w);
            a[4] = (short)f2bf(u1.x); a[5] = (short)f2bf(u1.y);
            a[6] = (short)f2bf(u1.z); a[7] = (short)f2bf(u1.w);
            afrag[s] = a;
        }

        floatx4 acc[8];
        floatx4 accE = (floatx4){0.f, 0.f, 0.f, 0.f};
        #pragma unroll
        for (int ct = 0; ct < 8; ++ct) acc[ct] = (floatx4){0.f, 0.f, 0.f, 0.f};

        #pragma unroll
        for (int ct = 0; ct < 8; ++ct) {
            #pragma unroll
            for (int s = 0; s < 4; ++s) {
                short8 b = *(const short8*)&Wl[(ct * 16 + col) * 136 + s * 32 + quad * 8];
                acc[ct] = __builtin_amdgcn_mfma_f32_16x16x32_bf16(afrag[s], b, acc[ct], 0, 0, 0);
            }
        }
        #pragma unroll
        for (int s = 0; s < 4; ++s) {
            short8 b = *(const short8*)&ABl[col * 136 + s * 32 + quad * 8];
            accE = __builtin_amdgcn_mfma_f32_16x16x32_bf16(afrag[s], b, accE, 0, 0, 0);
        }

        #pragma unroll
        for (int ct = 0; ct < 8; ++ct) {
            #pragma unroll
            for (int r = 0; r < 4; ++r) {
                feat_bf[(size_t)(n0 + quad * 4 + r) * FD + ct * 16 + col] = f2bf(acc[ct][r]);
            }
        }
        if (col < 8) {
            float* base = (col < 4) ? el : er;
            int hh = col & 3;
            #pragma unroll
            for (int r = 0; r < 4; ++r)
                base[(n0 + quad * 4 + r) * NH + hh] = accE[r];
        }
    }
}

// ---------------------------------------------------------------------------
// Kernel 2: per-edge weights wE[e][h] (edge-major float4) + fused CSR rows.
// Unshifted exp is exact-safe (logits sigma ~0.23). NT on streams.
// ---------------------------------------------------------------------------
__global__ void k_edgew(const float* __restrict__ el,
                        const float* __restrict__ er,
                        const int* __restrict__ src,
                        const int* __restrict__ dst,
                        float* __restrict__ wE,
                        int* __restrict__ rows) {
    int e = blockIdx.x * blockDim.x + threadIdx.x;
    if (e >= NE) return;
    int sj = __builtin_nontemporal_load(&src[e]);
    int dj = __builtin_nontemporal_load(&dst[e]);

    if (e == 0) {
        for (int n = 0; n <= dj; ++n) rows[n] = 0;
    } else {
        int prev = __builtin_nontemporal_load(&dst[e - 1]);
        for (int n = prev + 1; n <= dj; ++n) rows[n] = e;
    }
    if (e == NE - 1) {
        for (int n = dj + 1; n <= NN; ++n) rows[n] = NE;
    }

    float4 el4 = *(const float4*)&el[sj * NH];
    float4 er4 = *(const float4*)&er[dj * NH];
    float lg, z;
    float w0, w1, w2, w3;
    lg = el4.x + er4.x; z = fmaxf(lg, 0.2f * lg); w0 = __expf(z);
    lg = el4.y + er4.y; z = fmaxf(lg, 0.2f * lg); w1 = __expf(z);
    lg = el4.z + er4.z; z = fmaxf(lg, 0.2f * lg); w2 = __expf(z);
    lg = el4.w + er4.w; z = fmaxf(lg, 0.2f * lg); w3 = __expf(z);
    float* wp = &wE[e * NH];
    __builtin_nontemporal_store(w0, wp + 0);
    __builtin_nontemporal_store(w1, wp + 1);
    __builtin_nontemporal_store(w2, wp + 2);
    __builtin_nontemporal_store(w3, wp + 3);
}

// ---------------------------------------------------------------------------
// Kernel 3: aggregation (R4 structure). One wave per node; 4 edge slots x
// 16 dim lanes, x4 unroll -> 16 edges (32 cache lines) in flight. Tail edges
// masked with w=0. NT loads for src/wE streams (keep feat lines in L2),
// NT store for out.
// ---------------------------------------------------------------------------
__global__ __launch_bounds__(256) void k_aggregate(const unsigned short* __restrict__ feat_bf,
                                                   const float* __restrict__ wE,
                                                   const int* __restrict__ src,
                                                   const int* __restrict__ rows,
                                                   float* __restrict__ out) {
    const int wave = threadIdx.x >> 6;
    const int lane = threadIdx.x & 63;
    const int n = blockIdx.x * 4 + wave;
    if (n >= NN) return;

    const int s = rows[n], t = rows[n + 1];
    const int q  = lane >> 4;        // edge slot 0..3
    const int lp = lane & 15;        // dim slot: dims 8*lp .. 8*lp+7
    const int h  = lp >> 2;          // head of those dims
    const int dimoff = 8 * lp;

    float acc[8] = {0.f, 0.f, 0.f, 0.f, 0.f, 0.f, 0.f, 0.f};
    float den = 0.f;

    for (int e = s; e < t; e += 16) {
        int   sjv[4];
        float wv4[4];
        #pragma unroll
        for (int u = 0; u < 4; ++u) {
            int ei = e + 4 * u + q;
            int ec = (ei < t) ? ei : (t - 1);
            sjv[u] = __builtin_nontemporal_load(&src[ec]);
            wv4[u] = (ei < t) ? __builtin_nontemporal_load(&wE[ec * NH + h]) : 0.f;
        }
        uint4 uvv[4];
        #pragma unroll
        for (int u = 0; u < 4; ++u)
            uvv[u] = *(const uint4*)&feat_bf[(size_t)sjv[u] * FD + dimoff];
        #pragma unroll
        for (int u = 0; u < 4; ++u) {
            float w = wv4[u];
            uint4 uv = uvv[u];
            acc[0] += w * bf_lo(uv.x); acc[1] += w * bf_hi(uv.x);
            acc[2] += w * bf_lo(uv.y); acc[3] += w * bf_hi(uv.y);
            acc[4] += w * bf_lo(uv.z); acc[5] += w * bf_hi(uv.z);
            acc[6] += w * bf_lo(uv.w); acc[7] += w * bf_hi(uv.w);
            den += w;
        }
    }

    // combine the 4 edge-slot groups (lanes differing in bits 4,5)
    #pragma unroll
    for (int m = 16; m < 64; m <<= 1) {
        #pragma unroll
        for (int j = 0; j < 8; ++j) acc[j] += __shfl_xor(acc[j], m);
        den += __shfl_xor(den, m);
    }

    if (q == 0) {
        const float rden = (den > 0.f) ? 1.f / den : 0.f;
        float* op = out + (size_t)n * FD + dimoff;
        #pragma unroll
        for (int j = 0; j < 8; ++j)
            __builtin_nontemporal_store(acc[j] * rden, op + j);
    }
}

// ---------------------------------------------------------------------------
extern "C" void kernel_launch(void* const* d_in, const int* in_sizes, int n_in,
                              void* d_out, int out_size, void* d_ws, size_t ws_size,
                              hipStream_t stream) {
    const float* x  = (const float*)d_in[0];
    const float* W  = (const float*)d_in[1];
    const float* al = (const float*)d_in[2];
    const float* ar = (const float*)d_in[3];
    const int* src  = (const int*)d_in[4];
    const int* dst  = (const int*)d_in[5];
    float* out = (float*)d_out;

    // ws: feat_bf[NN*FD] ushort | el[NN*NH] | er[NN*NH] | rows[NN+1] | wE[NE*NH] | Gbf[16*128]
    unsigned short* feat_bf = (unsigned short*)d_ws;
    float* el = (float*)(feat_bf + (size_t)NN * FD);
    float* er = el + (size_t)NN * NH;
    int*   rows = (int*)(er + (size_t)NN * NH);
    float* wE = (float*)(((uintptr_t)(rows + NN + 1) + 15) & ~(uintptr_t)15);
    unsigned short* Gbf = (unsigned short*)(wE + (size_t)NE * NH);

    k_prep<<<8, 256, 0, stream>>>(W, al, ar, Gbf);
    k_gemm<<<392, 512, 0, stream>>>(x, W, Gbf, feat_bf, el, er);
    k_edgew<<<(NE + 255) / 256, 256, 0, stream>>>(el, er, src, dst, wE, rows);
    k_aggregate<<<(NN + 3) / 4, 256, 0, stream>>>(feat_bf, wE, src, rows, out);
}